// Round 6
// baseline (252.465 us; speedup 1.0000x reference)
//
#include <hip/hip_runtime.h>
#include <hip/hip_bf16.h>
#include <math.h>

#define B_  4
#define T_  1024
#define C_  768
#define H_  12
#define HD_ 64
#define M_  (B_*T_)     // 4096 rows
#define C3_ (3*C_)      // 2304
#define C4_ (4*C_)      // 3072

typedef __bf16 bf16;
typedef bf16  bf16x2 __attribute__((ext_vector_type(2)));
typedef bf16  bf16x8 __attribute__((ext_vector_type(8)));
typedef float f32x4  __attribute__((ext_vector_type(4)));

__device__ __forceinline__ f32x4 mfma16(bf16x8 a, bf16x8 b, f32x4 c) {
    return __builtin_amdgcn_mfma_f32_16x16x32_bf16(a, b, c, 0, 0, 0);
}

#define GLOAD_LDS16(g, l)                                                     \
    __builtin_amdgcn_global_load_lds(                                         \
        (const __attribute__((address_space(1))) void*)(g),                   \
        (__attribute__((address_space(3))) void*)(l), 16, 0, 0)

// ---------------------------------------------------------------------------
// Transpose + cast: in fp32 [K,N] -> out bf16 [N,K]
// ---------------------------------------------------------------------------
__global__ void transpose_cast_kernel(const float* __restrict__ in,
                                      bf16* __restrict__ out, int K, int N) {
    __shared__ float tile[32][33];
    int n0 = blockIdx.x * 32, k0 = blockIdx.y * 32;
    int tx = threadIdx.x, ty = threadIdx.y;  // 32 x 8
#pragma unroll
    for (int i = 0; i < 32; i += 8)
        tile[ty + i][tx] = in[(size_t)(k0 + ty + i) * N + n0 + tx];
    __syncthreads();
#pragma unroll
    for (int i = 0; i < 32; i += 8)
        out[(size_t)(n0 + ty + i) * K + k0 + tx] = (bf16)tile[tx][ty + i];
}

// ---------------------------------------------------------------------------
// LayerNorm: fp32 in [rows, 768] -> bf16 out. One block (256 thr) per row.
// ---------------------------------------------------------------------------
__device__ __forceinline__ float block_sum256(float v, float* red, int tid) {
#pragma unroll
    for (int m = 32; m >= 1; m >>= 1) v += __shfl_xor(v, m, 64);
    if ((tid & 63) == 0) red[tid >> 6] = v;
    __syncthreads();
    v = red[0] + red[1] + red[2] + red[3];
    __syncthreads();
    return v;
}

__global__ __launch_bounds__(256) void ln_kernel(const float* __restrict__ in,
                                                 const float* __restrict__ scale,
                                                 const float* __restrict__ bias,
                                                 bf16* __restrict__ out) {
    __shared__ float red[4];
    int row = blockIdx.x, tid = threadIdx.x;
    const float* p = in + (size_t)row * C_;
    float v0 = p[tid], v1 = p[tid + 256], v2 = p[tid + 512];
    float mu = block_sum256(v0 + v1 + v2, red, tid) * (1.0f / C_);
    float d0 = v0 - mu, d1 = v1 - mu, d2 = v2 - mu;
    float var = block_sum256(d0 * d0 + d1 * d1 + d2 * d2, red, tid) * (1.0f / C_);
    float rstd = rsqrtf(var + 1e-5f);
    bf16* o = out + (size_t)row * C_;
    o[tid]       = (bf16)(d0 * rstd * scale[tid]       + bias[tid]);
    o[tid + 256] = (bf16)(d1 * rstd * scale[tid + 256] + bias[tid + 256]);
    o[tid + 512] = (bf16)(d2 * rstd * scale[tid + 512] + bias[tid + 512]);
}

// ---------------------------------------------------------------------------
// 8-phase-style GEMM: C[M,N] = A[M,K] * BT[N,K]^T (+epilogue).
// BM=256, BN=128, BK=64. 8 waves (4M x 2N), wave tile 64x64 (4x4 16x16 frags).
// 3 LDS buffers, depth-2 K-tile prefetch, counted vmcnt(6) (T3/T4).
// 2 fine phases per K-tile (T5 setprio around MFMA). XOR-swizzled LDS via
// pre-swizzled global source + swizzled read (T2, rule #21).
// NOTE: STAGE macros take K-offset in ELEMENTS (round-5 bug: macro re-scaled
// an already-scaled offset by 64 -> staged garbage -> NaN).
// ---------------------------------------------------------------------------
enum { EPI_BF16 = 0, EPI_RES_F32 = 1, EPI_GELU_BF16 = 2, EPI_PARTIAL = 3 };

template <int EPI>
__global__ __launch_bounds__(512, 2) void gemm256_kernel(
    const bf16* __restrict__ A, const bf16* __restrict__ BT,
    const float* __restrict__ bias, const float* __restrict__ res,
    void* __restrict__ outv, int N, int Ktot, int nx) {
    __shared__ bf16 Al[3][256 * 64];   // 96 KiB
    __shared__ bf16 Bl[3][128 * 64];   // 48 KiB
    const int tid = threadIdx.x;
    const int l = tid & 63, w = tid >> 6;
    const int wm = w >> 1, wn = w & 1;           // 4M x 2N waves
    // bijective XCD-chunked swizzle (gridDim.x divisible by 8)
    const int cpx = gridDim.x >> 3;
    const int wg = (blockIdx.x & 7) * cpx + (blockIdx.x >> 3);
    const int bm = (wg / nx) * 256, bn = (wg % nx) * 128;
    const int Kper = Ktot / gridDim.y;
    const int k0 = blockIdx.y * Kper;
    const int lr = l & 15, lh = l >> 4;

    // --- staging: LDS chunk i=(row*8+c) holds global k-chunk c^(row&7).
    // thread tid covers chunks {tid + j*512}; row=srow+j*64, c=tid&7 (inv.)
    const int srow = tid >> 3;
    const int scol = ((tid & 7) ^ (srow & 7)) * 8;
    const bf16* gA = A + (size_t)(bm + srow) * Ktot + k0 + scol;
    const bf16* gB = BT + (size_t)(bn + srow) * Ktot + k0 + scol;

// koff is the K offset in ELEMENTS within this block's K-slice.
#define G256_STAGE_A(buf, koff)                                                \
    {                                                                          \
        GLOAD_LDS16(gA + (koff), &Al[buf][tid * 8]);                           \
        GLOAD_LDS16(gA + (size_t)64 * Ktot + (koff),                           \
                    &Al[buf][(tid + 512) * 8]);                                \
        GLOAD_LDS16(gA + (size_t)128 * Ktot + (koff),                          \
                    &Al[buf][(tid + 1024) * 8]);                               \
    }
#define G256_STAGE_B(buf, koff)                                                \
    {                                                                          \
        GLOAD_LDS16(gA + (size_t)192 * Ktot + (koff),                          \
                    &Al[buf][(tid + 1536) * 8]);                               \
        GLOAD_LDS16(gB + (koff), &Bl[buf][tid * 8]);                           \
        GLOAD_LDS16(gB + (size_t)64 * Ktot + (koff),                           \
                    &Bl[buf][(tid + 512) * 8]);                                \
    }

    // read-side swizzled chunk offsets (elements): kk0 -> x0, kk1 -> x0^32
    const int x0 = (lh ^ (lr & 7)) * 8;
    const int x1 = x0 ^ 32;

    f32x4 acc[4][4] = {};
    const int NT = Kper >> 6;  // K-tiles of 64 (>= 12 in all uses)

    G256_STAGE_A(0, 0); G256_STAGE_B(0, 0);
    G256_STAGE_A(1, 64); G256_STAGE_B(1, 64);
    asm volatile("s_waitcnt vmcnt(6)" ::: "memory");  // tile 0 resident
    __builtin_amdgcn_s_barrier();

    int cur = 0, sb = 2;
    bf16x8 a[4][2], bq[2][2];
    for (int t = 0; t < NT; ++t) {
        const int kt = t * 64;
        // ---- phase 0: A m0-3 + B n0-1, MFMA quad (m0-3 x n0-1) ----
        if (t + 2 < NT) G256_STAGE_A(sb, kt + 128);
#pragma unroll
        for (int mt = 0; mt < 4; ++mt) {
            const bf16* ar = &Al[cur][(wm * 64 + mt * 16 + lr) * 64];
            a[mt][0] = *(const bf16x8*)(ar + x0);
            a[mt][1] = *(const bf16x8*)(ar + x1);
        }
#pragma unroll
        for (int nt = 0; nt < 2; ++nt) {
            const bf16* br = &Bl[cur][(wn * 64 + nt * 16 + lr) * 64];
            bq[nt][0] = *(const bf16x8*)(br + x0);
            bq[nt][1] = *(const bf16x8*)(br + x1);
        }
        __builtin_amdgcn_s_barrier();
        __builtin_amdgcn_s_setprio(1);
#pragma unroll
        for (int kk = 0; kk < 2; ++kk)
#pragma unroll
            for (int mt = 0; mt < 4; ++mt)
#pragma unroll
                for (int nt = 0; nt < 2; ++nt)
                    acc[mt][nt] = mfma16(a[mt][kk], bq[nt][kk], acc[mt][nt]);
        __builtin_amdgcn_s_setprio(0);
        __builtin_amdgcn_s_barrier();

        // ---- phase 1: B n2-3, MFMA quad (m0-3 x n2-3) ----
        if (t + 2 < NT) G256_STAGE_B(sb, kt + 128);
#pragma unroll
        for (int nt = 0; nt < 2; ++nt) {
            const bf16* br = &Bl[cur][(wn * 64 + (nt + 2) * 16 + lr) * 64];
            bq[nt][0] = *(const bf16x8*)(br + x0);
            bq[nt][1] = *(const bf16x8*)(br + x1);
        }
        __builtin_amdgcn_s_barrier();
        __builtin_amdgcn_s_setprio(1);
#pragma unroll
        for (int kk = 0; kk < 2; ++kk)
#pragma unroll
            for (int mt = 0; mt < 4; ++mt)
#pragma unroll
                for (int nt = 0; nt < 2; ++nt)
                    acc[mt][nt + 2] =
                        mfma16(a[mt][kk], bq[nt][kk], acc[mt][nt + 2]);
        __builtin_amdgcn_s_setprio(0);
        // counted drain: keep tile t+2's 6 loads in flight, ensure t+1 ready
        if (t + 2 < NT) {
            asm volatile("s_waitcnt vmcnt(6)" ::: "memory");
        } else {
            asm volatile("s_waitcnt vmcnt(0)" ::: "memory");
        }
        __builtin_amdgcn_s_barrier();

        cur = (cur == 2) ? 0 : cur + 1;
        sb = (sb == 2) ? 0 : sb + 1;
    }
#undef G256_STAGE_A
#undef G256_STAGE_B

#pragma unroll
    for (int mt = 0; mt < 4; ++mt) {
#pragma unroll
        for (int nt = 0; nt < 4; ++nt) {
#pragma unroll
            for (int r = 0; r < 4; ++r) {
                int row = bm + wm * 64 + mt * 16 + lh * 4 + r;
                int col = bn + wn * 64 + nt * 16 + lr;
                if (EPI == EPI_PARTIAL) {
                    ((float*)outv)[(size_t)blockIdx.y * M_ * N +
                                   (size_t)row * N + col] = acc[mt][nt][r];
                } else {
                    float v = acc[mt][nt][r] + bias[col];
                    if (EPI == EPI_RES_F32) {
                        ((float*)outv)[(size_t)row * N + col] =
                            v + res[(size_t)row * N + col];
                    } else if (EPI == EPI_GELU_BF16) {
                        float x4 = v * v * v * v;  // faithful: no leading x+
                        float g = 0.5f * v *
                                  (1.0f + tanhf(0.7978845608028654f * 0.044715f * x4));
                        ((bf16*)outv)[(size_t)row * N + col] = (bf16)g;
                    } else {
                        ((bf16*)outv)[(size_t)row * N + col] = (bf16)v;
                    }
                }
            }
        }
    }
}

// ---------------------------------------------------------------------------
// Split-K=2 reduce: out = part0 + part1 + bias + res   (fp32, float4)
// ---------------------------------------------------------------------------
__global__ __launch_bounds__(256) void reduce2_kernel(const float* __restrict__ part,
                                                      const float* __restrict__ bias,
                                                      const float* __restrict__ res,
                                                      float* __restrict__ out) {
    const size_t MN = (size_t)M_ * C_;
    size_t i = ((size_t)blockIdx.x * 256 + threadIdx.x) * 4;
    if (i >= MN) return;
    f32x4 a = *(const f32x4*)(part + i);
    f32x4 b = *(const f32x4*)(part + MN + i);
    f32x4 r = *(const f32x4*)(res + i);
    f32x4 bi = *(const f32x4*)(bias + (int)(i % C_));
    *(f32x4*)(out + i) = a + b + r + bi;
}

// ---------------------------------------------------------------------------
// V pre-transpose: qkv V-part [t][d] per head -> vt[(b*H+h)][d=64][T=1024]
// ---------------------------------------------------------------------------
__global__ __launch_bounds__(256) void vtrans_kernel(const bf16* __restrict__ qkv,
                                                     bf16* __restrict__ vt) {
    __shared__ bf16 tl[64 * 64];
    const int tid = threadIdx.x;
    const int t0 = blockIdx.x * 64;
    const int hv = blockIdx.y;          // b*H + h
    const int b = hv / H_, h = hv % H_;
    const int src0 = h * 192 + 128;
#pragma unroll
    for (int c = 0; c < 2; ++c) {
        int i = tid + c * 256;
        int row = i >> 3, seg = i & 7;  // row = t-within-tile
        bf16x8 v = *(const bf16x8*)(qkv + (size_t)(b * T_ + t0 + row) * C3_ +
                                    src0 + seg * 8);
        *(bf16x8*)(tl + row * 64 + ((seg ^ (row & 7)) * 8)) = v;
    }
    __syncthreads();
#pragma unroll
    for (int c = 0; c < 2; ++c) {
        int i = tid + c * 256;
        int d = i >> 3, ts = i & 7;
        bf16x8 o;
#pragma unroll
        for (int j = 0; j < 8; ++j)
            o[j] = tl[(ts * 8 + j) * 64 + (d ^ (j * 8))];
        *(bf16x8*)(vt + (size_t)(hv * 64 + d) * T_ + t0 + ts * 8) = o;
    }
}

// ---------------------------------------------------------------------------
// Causal flash attention, swapped-QK^T. Depth-2 prefetch (3 buffers),
// raw s_barrier + counted vmcnt. Grid 768 flat, XCD-grouped per (b,h).
// ---------------------------------------------------------------------------
__global__ __launch_bounds__(256) void attn_kernel(const bf16* __restrict__ qkv,
                                                   const bf16* __restrict__ vt,
                                                   bf16* __restrict__ y) {
    const int flat = blockIdx.x;
    const int g = (flat & 7) * 6 + (flat >> 3) / 16;  // 0..47 = b*H+h
    const int qt = (flat >> 3) & 15;
    const int h = g % H_, b = g / H_, hv = g;

    const int tid = threadIdx.x, l = tid & 63, w = tid >> 6;
    const int lr = l & 15, lh = l >> 4, d0 = lh * 8;
    const int bc = h * 192;

    __shared__ bf16 Kl[3][64 * 64];
    __shared__ bf16 Vl[3][64 * 64];
    __shared__ bf16 Pl[4][16 * 64];

    const int qg = qt * 64 + w * 16 + lr;
    const bf16* qp = qkv + (size_t)(b * T_ + qg) * C3_ + bc;
    bf16x8 qf0 = *(const bf16x8*)(qp + d0);
    bf16x8 qf1 = *(const bf16x8*)(qp + 32 + d0);

    const int srow = tid >> 3;
    const int ss = (tid & 7) ^ (srow & 7);
    const bf16* k0p = qkv + (size_t)(b * T_ + srow) * C3_ + bc + 64 + ss * 8;
    const bf16* k1p = k0p + (size_t)32 * C3_;
    const bf16* v0p = vt + (size_t)(hv * 64 + srow) * T_ + ss * 8;
    const bf16* v1p = v0p + (size_t)32 * T_;

#define ATTN_STAGE(buf, kc)                                                    \
    {                                                                          \
        GLOAD_LDS16(k0p + (size_t)(kc) * 64 * C3_, &Kl[buf][tid * 8]);         \
        GLOAD_LDS16(v0p + (kc) * 64, &Vl[buf][tid * 8]);                       \
        GLOAD_LDS16(k1p + (size_t)(kc) * 64 * C3_, &Kl[buf][(tid + 256) * 8]); \
        GLOAD_LDS16(v1p + (kc) * 64, &Vl[buf][(tid + 256) * 8]);               \
    }

    f32x4 acc_o[4] = {};
    float m_run = -1e30f, l_run = 0.f;
    const float SCL = 0.125f * 1.44269504089f;  // 1/sqrt(HD) * log2(e)

    ATTN_STAGE(0, 0);
    if (qt >= 1) ATTN_STAGE(1, 1);

    int cur = 0, nxt = 2;
    for (int kc = 0; kc <= qt; ++kc) {
        if (kc + 2 <= qt) {
            ATTN_STAGE(nxt, kc + 2);
            asm volatile("s_waitcnt vmcnt(8)" ::: "memory");
        } else if (kc + 1 <= qt) {
            asm volatile("s_waitcnt vmcnt(4)" ::: "memory");
        } else {
            asm volatile("s_waitcnt vmcnt(0)" ::: "memory");
        }
        __builtin_amdgcn_s_barrier();  // K/V stage(kc) visible

        const bf16* Kb = Kl[cur];
        const bf16* Vb = Vl[cur];

        // S^T = K Q^T : lane holds S[k = kc*64+nt*16+lh*4+r][q = qg]
        f32x4 st[4];
#pragma unroll
        for (int nt = 0; nt < 4; ++nt) {
            int R = nt * 16 + lr;
            const bf16* kb = Kb + R * 64;
            bf16x8 k0 = *(const bf16x8*)(kb + (lh ^ (R & 7)) * 8);
            bf16x8 k1 = *(const bf16x8*)(kb + ((4 + lh) ^ (R & 7)) * 8);
            f32x4 a = {};
            a = mfma16(k0, qf0, a);
            st[nt] = mfma16(k1, qf1, a);
        }

        // softmax in log2 domain; lane owns q-row qg, 16 k-values
        const int diag = (kc == qt);
        float p[16], pmax = -1e30f;
#pragma unroll
        for (int nt = 0; nt < 4; ++nt)
#pragma unroll
            for (int r = 0; r < 4; ++r) {
                float v = st[nt][r] * SCL;
                if (diag) {
                    int kg = kc * 64 + nt * 16 + lh * 4 + r;
                    if (kg > qg) v = -1e38f;
                }
                p[nt * 4 + r] = v;
                pmax = fmaxf(pmax, v);
            }
        pmax = fmaxf(pmax, __shfl_xor(pmax, 16, 64));
        pmax = fmaxf(pmax, __shfl_xor(pmax, 32, 64));

        if (!__all(pmax - m_run <= 8.0f)) {  // defer-max (T13), THR=8 (log2)
            float mnew = fmaxf(m_run, pmax);
            float sc = exp2f(m_run - mnew);
            l_run *= sc;
            m_run = mnew;
#pragma unroll
            for (int r = 0; r < 4; ++r) {
                float sq = __shfl(sc, lh * 4 + r, 64);
#pragma unroll
                for (int nt = 0; nt < 4; ++nt) acc_o[nt][r] *= sq;
            }
        }

        float lsum = 0.f;
#pragma unroll
        for (int i = 0; i < 16; ++i) {
            p[i] = exp2f(p[i] - m_run);
            lsum += p[i];
        }
        lsum += __shfl_xor(lsum, 16, 64);
        lsum += __shfl_xor(lsum, 32, 64);
        l_run += lsum;

        // P -> Pl[q_local = lr][k], swizzled rows
        {
            char* pw = (char*)&Pl[w][0];
            int swz = (lr & 7) << 4;
#pragma unroll
            for (int nt = 0; nt < 4; ++nt)
#pragma unroll
                for (int rr = 0; rr < 2; ++rr) {
                    int kk = nt * 16 + lh * 4 + rr * 2;
                    bf16x2 pr = {(bf16)p[nt * 4 + rr * 2],
                                 (bf16)p[nt * 4 + rr * 2 + 1]};
                    *(bf16x2*)(pw + lr * 128 + ((kk * 2) ^ swz)) = pr;
                }
        }

        // PV: a-frag = Pl rows (q_local), b-frag = Vl rows (d)
        {
            const bf16* pb = &Pl[w][0] + lr * 64;
            bf16x8 pa0 = *(const bf16x8*)(pb + (lh ^ (lr & 7)) * 8);
            bf16x8 pa1 = *(const bf16x8*)(pb + ((4 + lh) ^ (lr & 7)) * 8);
#pragma unroll
            for (int nt = 0; nt < 4; ++nt) {
                int R = nt * 16 + lr;
                const bf16* vb = Vb + R * 64;
                bf16x8 v0 = *(const bf16x8*)(vb + (lh ^ (R & 7)) * 8);
                bf16x8 v1 = *(const bf16x8*)(vb + ((4 + lh) ^ (R & 7)) * 8);
                acc_o[nt] = mfma16(pa0, v0, acc_o[nt]);
                acc_o[nt] = mfma16(pa1, v1, acc_o[nt]);
            }
        }
        asm volatile("s_waitcnt lgkmcnt(0)" ::: "memory");
        __builtin_amdgcn_s_barrier();  // all reads of buf[cur] done

        cur = (cur == 2) ? 0 : cur + 1;
        nxt = (nxt == 2) ? 0 : nxt + 1;
    }

    float rl = 1.0f / l_run;
#pragma unroll
    for (int r = 0; r < 4; ++r) {
        float rq = __shfl(rl, lh * 4 + r, 64);
        int q = qt * 64 + w * 16 + lh * 4 + r;
#pragma unroll
        for (int nt = 0; nt < 4; ++nt)
            y[(size_t)(b * T_ + q) * C_ + h * 64 + nt * 16 + lr] =
                (bf16)(acc_o[nt][r] * rq);
    }
#undef ATTN_STAGE
}

// ---------------------------------------------------------------------------
extern "C" void kernel_launch(void* const* d_in, const int* in_sizes, int n_in,
                              void* d_out, int out_size, void* d_ws, size_t ws_size,
                              hipStream_t stream) {
    (void)in_sizes; (void)n_in; (void)out_size; (void)ws_size;
    const float* x     = (const float*)d_in[0];
    const float* ln1_s = (const float*)d_in[1];
    const float* ln1_b = (const float*)d_in[2];
    const float* Wqkv  = (const float*)d_in[3];
    const float* bqkv  = (const float*)d_in[4];
    const float* Wo    = (const float*)d_in[5];
    const float* bo    = (const float*)d_in[6];
    const float* ln2_s = (const float*)d_in[7];
    const float* ln2_b = (const float*)d_in[8];
    const float* Wfc   = (const float*)d_in[9];
    const float* bfc   = (const float*)d_in[10];
    const float* Wproj = (const float*)d_in[11];
    const float* bproj = (const float*)d_in[12];

    char* ws = (char*)d_ws;
    float* x2     = (float*)(ws);
    bf16*  vtbuf  = (bf16*)(ws);                      // aliases x2 (live: vtrans..attn)
    bf16*  fcbuf  = (bf16*)(ws + 12582912);
    bf16*  WprojT = (bf16*)(ws + 37748736);
    bf16*  lnbuf  = (bf16*)(ws + 42467328);
    float* parts  = (float*)(ws + 42467328);          // aliases lnbuf+qkv (live: proj..reduce)
    bf16*  qkv    = (bf16*)(ws + 48758784);
    bf16*  WqkvT  = (bf16*)(ws + 67633152);
    bf16*  WoT    = (bf16*)(ws + 71172096);
    bf16*  WfcT   = (bf16*)(ws + 72351744);

    dim3 tb(32, 8);
    transpose_cast_kernel<<<dim3(C3_ / 32, C_ / 32), tb, 0, stream>>>(Wqkv, WqkvT, C_, C3_);
    transpose_cast_kernel<<<dim3(C_ / 32, C_ / 32), tb, 0, stream>>>(Wo, WoT, C_, C_);
    transpose_cast_kernel<<<dim3(C4_ / 32, C_ / 32), tb, 0, stream>>>(Wfc, WfcT, C_, C4_);
    transpose_cast_kernel<<<dim3(C_ / 32, C4_ / 32), tb, 0, stream>>>(Wproj, WprojT, C4_, C_);

    ln_kernel<<<M_, 256, 0, stream>>>(x, ln1_s, ln1_b, lnbuf);

    gemm256_kernel<EPI_BF16><<<dim3(288, 1), 512, 0, stream>>>(
        lnbuf, WqkvT, bqkv, nullptr, qkv, C3_, C_, 18);

    vtrans_kernel<<<dim3(T_ / 64, B_ * H_), 256, 0, stream>>>(qkv, vtbuf);

    attn_kernel<<<dim3(768), 256, 0, stream>>>(qkv, vtbuf, lnbuf);

    gemm256_kernel<EPI_RES_F32><<<dim3(96, 1), 512, 0, stream>>>(
        lnbuf, WoT, bo, x, x2, C_, C_, 6);

    ln_kernel<<<M_, 256, 0, stream>>>(x2, ln2_s, ln2_b, lnbuf);

    gemm256_kernel<EPI_GELU_BF16><<<dim3(384, 1), 512, 0, stream>>>(
        lnbuf, WfcT, bfc, nullptr, fcbuf, C4_, C_, 24);

    gemm256_kernel<EPI_PARTIAL><<<dim3(96, 2), 512, 0, stream>>>(
        fcbuf, WprojT, nullptr, nullptr, parts, C_, C4_, 6);

    reduce2_kernel<<<dim3((M_ * C_) / 1024), 256, 0, stream>>>(parts, bproj, x2,
                                                               (float*)d_out);
}

// Round 7
// 223.441 us; speedup vs baseline: 1.1299x; 1.1299x over previous
//
#include <hip/hip_runtime.h>
#include <hip/hip_bf16.h>
#include <math.h>

#define B_  4
#define T_  1024
#define C_  768
#define H_  12
#define HD_ 64
#define M_  (B_*T_)     // 4096 rows
#define C3_ (3*C_)      // 2304
#define C4_ (4*C_)      // 3072

typedef __bf16 bf16;
typedef bf16  bf16x2 __attribute__((ext_vector_type(2)));
typedef bf16  bf16x8 __attribute__((ext_vector_type(8)));
typedef float f32x4  __attribute__((ext_vector_type(4)));

__device__ __forceinline__ f32x4 mfma16(bf16x8 a, bf16x8 b, f32x4 c) {
    return __builtin_amdgcn_mfma_f32_16x16x32_bf16(a, b, c, 0, 0, 0);
}

#define GLOAD_LDS16(g, l)                                                     \
    __builtin_amdgcn_global_load_lds(                                         \
        (const __attribute__((address_space(1))) void*)(g),                   \
        (__attribute__((address_space(3))) void*)(l), 16, 0, 0)

// ---------------------------------------------------------------------------
// Transpose + cast: in fp32 [K,N] -> out bf16 [N,K]
// ---------------------------------------------------------------------------
__global__ void transpose_cast_kernel(const float* __restrict__ in,
                                      bf16* __restrict__ out, int K, int N) {
    __shared__ float tile[32][33];
    int n0 = blockIdx.x * 32, k0 = blockIdx.y * 32;
    int tx = threadIdx.x, ty = threadIdx.y;  // 32 x 8
#pragma unroll
    for (int i = 0; i < 32; i += 8)
        tile[ty + i][tx] = in[(size_t)(k0 + ty + i) * N + n0 + tx];
    __syncthreads();
#pragma unroll
    for (int i = 0; i < 32; i += 8)
        out[(size_t)(n0 + ty + i) * K + k0 + tx] = (bf16)tile[tx][ty + i];
}

// ---------------------------------------------------------------------------
// LayerNorm: fp32 in [rows, 768] -> bf16 out. One block (256 thr) per row.
// ---------------------------------------------------------------------------
__device__ __forceinline__ float block_sum256(float v, float* red, int tid) {
#pragma unroll
    for (int m = 32; m >= 1; m >>= 1) v += __shfl_xor(v, m, 64);
    if ((tid & 63) == 0) red[tid >> 6] = v;
    __syncthreads();
    v = red[0] + red[1] + red[2] + red[3];
    __syncthreads();
    return v;
}

__global__ __launch_bounds__(256) void ln_kernel(const float* __restrict__ in,
                                                 const float* __restrict__ scale,
                                                 const float* __restrict__ bias,
                                                 bf16* __restrict__ out) {
    __shared__ float red[4];
    int row = blockIdx.x, tid = threadIdx.x;
    const float* p = in + (size_t)row * C_;
    float v0 = p[tid], v1 = p[tid + 256], v2 = p[tid + 512];
    float mu = block_sum256(v0 + v1 + v2, red, tid) * (1.0f / C_);
    float d0 = v0 - mu, d1 = v1 - mu, d2 = v2 - mu;
    float var = block_sum256(d0 * d0 + d1 * d1 + d2 * d2, red, tid) * (1.0f / C_);
    float rstd = rsqrtf(var + 1e-5f);
    bf16* o = out + (size_t)row * C_;
    o[tid]       = (bf16)(d0 * rstd * scale[tid]       + bias[tid]);
    o[tid + 256] = (bf16)(d1 * rstd * scale[tid + 256] + bias[tid + 256]);
    o[tid + 512] = (bf16)(d2 * rstd * scale[tid + 512] + bias[tid + 512]);
}

// ---------------------------------------------------------------------------
// GEMM: C[M,N] = A[M,K] * BT[N,K]^T (+epilogue). BM=128, BN=256, BK=32.
// 4 waves (2M x 2N), wave tile 64x128 -> 32 MFMA per 12 ds_read_b128 per
// K-step (MFMA-dominant, vs 16:8 at 64x64). 3 LDS buffers (72 KiB) ->
// 2 blocks/CU; ALL grids fully co-resident (<=512 blocks). Round-4 proven
// 2-phase loop: depth-2 prefetch, counted vmcnt(12/6/0), swizzle
// c^((row>>1)&3) (measured 0 bank conflicts).
// ---------------------------------------------------------------------------
enum { EPI_BF16 = 0, EPI_RES_F32 = 1, EPI_GELU_BF16 = 2, EPI_PARTIAL = 3 };

template <int EPI>
__global__ __launch_bounds__(256, 2) void gemm_kernel(
    const bf16* __restrict__ A, const bf16* __restrict__ BT,
    const float* __restrict__ bias, const float* __restrict__ res,
    void* __restrict__ outv, int N, int Ktot, int nx) {
    __shared__ bf16 Al[3][128 * 32];   // 24 KiB
    __shared__ bf16 Bl[3][256 * 32];   // 48 KiB
    const int tid = threadIdx.x;
    const int l = tid & 63, w = tid >> 6;
    const int wm = w >> 1, wn = w & 1;
    // bijective XCD-chunked swizzle (gridDim.x divisible by 8)
    const int cpx = gridDim.x >> 3;
    const int wg = (blockIdx.x & 7) * cpx + (blockIdx.x >> 3);
    const int bm = (wg / nx) * 128, bn = (wg % nx) * 256;
    const int Kper = Ktot / gridDim.y;
    const int k0 = blockIdx.y * Kper;
    const int lr = l & 15, lh = l >> 4;

    // staging: LDS chunk (row, c) holds global k-chunk c ^ ((row>>1)&3).
    // thread tid covers rows {srow + j*64}; xor term invariant across j.
    const int srow = tid >> 2;
    const int scol = ((tid & 3) ^ ((srow >> 1) & 3)) * 8;
    const bf16* gA = A + (size_t)(bm + srow) * Ktot + k0 + scol;
    const bf16* gB = BT + (size_t)(bn + srow) * Ktot + k0 + scol;

// koff = K offset in ELEMENTS within this block's K-slice.
#define GEMM_STAGE(buf, koff)                                                  \
    {                                                                          \
        GLOAD_LDS16(gA + (koff), &Al[buf][tid * 8]);                           \
        GLOAD_LDS16(gA + (size_t)64 * Ktot + (koff),                           \
                    &Al[buf][(tid + 256) * 8]);                                \
        GLOAD_LDS16(gB + (koff), &Bl[buf][tid * 8]);                           \
        GLOAD_LDS16(gB + (size_t)64 * Ktot + (koff),                           \
                    &Bl[buf][(tid + 256) * 8]);                                \
        GLOAD_LDS16(gB + (size_t)128 * Ktot + (koff),                          \
                    &Bl[buf][(tid + 512) * 8]);                                \
        GLOAD_LDS16(gB + (size_t)192 * Ktot + (koff),                          \
                    &Bl[buf][(tid + 768) * 8]);                                \
    }

    // read-side swizzled chunk offset (elements) within a 32-elem row
    const int rdoff = (lh ^ ((lr >> 1) & 3)) * 8;

    f32x4 acc[4][8] = {};
    const int nk = Kper >> 5;

    GEMM_STAGE(0, 0);
    GEMM_STAGE(1, 32);
    asm volatile("s_waitcnt vmcnt(6)" ::: "memory");  // tile 0 resident
    __builtin_amdgcn_s_barrier();

    int cur = 0, sb = 2;
    for (int t = 0; t < nk; ++t) {
        if (t + 2 < nk) {
            GEMM_STAGE(sb, (t + 2) * 32);
            asm volatile("s_waitcnt vmcnt(12)" ::: "memory");
        } else if (t + 1 < nk) {
            asm volatile("s_waitcnt vmcnt(6)" ::: "memory");
        } else {
            asm volatile("s_waitcnt vmcnt(0)" ::: "memory");
        }
        __builtin_amdgcn_s_barrier();  // stage(t) visible to all waves

        bf16x8 af[4], bfr[8];
#pragma unroll
        for (int mt = 0; mt < 4; ++mt)
            af[mt] = *(const bf16x8*)(&Al[cur][(wm * 64 + mt * 16 + lr) * 32 + rdoff]);
#pragma unroll
        for (int nt = 0; nt < 8; ++nt)
            bfr[nt] = *(const bf16x8*)(&Bl[cur][(wn * 128 + nt * 16 + lr) * 32 + rdoff]);
        asm volatile("s_waitcnt lgkmcnt(0)" ::: "memory");
        __builtin_amdgcn_s_barrier();  // all reads of buf[cur] done

        __builtin_amdgcn_s_setprio(1);
#pragma unroll
        for (int mt = 0; mt < 4; ++mt)
#pragma unroll
            for (int nt = 0; nt < 8; ++nt)
                acc[mt][nt] = mfma16(af[mt], bfr[nt], acc[mt][nt]);
        __builtin_amdgcn_s_setprio(0);

        cur = (cur == 2) ? 0 : cur + 1;
        sb = (sb == 2) ? 0 : sb + 1;
    }
#undef GEMM_STAGE

#pragma unroll
    for (int mt = 0; mt < 4; ++mt) {
#pragma unroll
        for (int nt = 0; nt < 8; ++nt) {
#pragma unroll
            for (int r = 0; r < 4; ++r) {
                int row = bm + wm * 64 + mt * 16 + lh * 4 + r;
                int col = bn + wn * 128 + nt * 16 + lr;
                if (EPI == EPI_PARTIAL) {
                    ((float*)outv)[(size_t)blockIdx.y * M_ * N +
                                   (size_t)row * N + col] = acc[mt][nt][r];
                } else {
                    float v = acc[mt][nt][r] + bias[col];
                    if (EPI == EPI_RES_F32) {
                        ((float*)outv)[(size_t)row * N + col] =
                            v + res[(size_t)row * N + col];
                    } else if (EPI == EPI_GELU_BF16) {
                        float x4 = v * v * v * v;  // faithful: no leading x+
                        float g = 0.5f * v *
                                  (1.0f + tanhf(0.7978845608028654f * 0.044715f * x4));
                        ((bf16*)outv)[(size_t)row * N + col] = (bf16)g;
                    } else {
                        ((bf16*)outv)[(size_t)row * N + col] = (bf16)v;
                    }
                }
            }
        }
    }
}

// ---------------------------------------------------------------------------
// Split-K=2 reduce: out = part0 + part1 + bias + res   (fp32, float4)
// ---------------------------------------------------------------------------
__global__ __launch_bounds__(256) void reduce2_kernel(const float* __restrict__ part,
                                                      const float* __restrict__ bias,
                                                      const float* __restrict__ res,
                                                      float* __restrict__ out) {
    const size_t MN = (size_t)M_ * C_;
    size_t i = ((size_t)blockIdx.x * 256 + threadIdx.x) * 4;
    if (i >= MN) return;
    f32x4 a = *(const f32x4*)(part + i);
    f32x4 b = *(const f32x4*)(part + MN + i);
    f32x4 r = *(const f32x4*)(res + i);
    f32x4 bi = *(const f32x4*)(bias + (int)(i % C_));
    *(f32x4*)(out + i) = a + b + r + bi;
}

// ---------------------------------------------------------------------------
// V pre-transpose: qkv V-part [t][d] per head -> vt[(b*H+h)][d=64][T=1024]
// ---------------------------------------------------------------------------
__global__ __launch_bounds__(256) void vtrans_kernel(const bf16* __restrict__ qkv,
                                                     bf16* __restrict__ vt) {
    __shared__ bf16 tl[64 * 64];
    const int tid = threadIdx.x;
    const int t0 = blockIdx.x * 64;
    const int hv = blockIdx.y;          // b*H + h
    const int b = hv / H_, h = hv % H_;
    const int src0 = h * 192 + 128;
#pragma unroll
    for (int c = 0; c < 2; ++c) {
        int i = tid + c * 256;
        int row = i >> 3, seg = i & 7;  // row = t-within-tile
        bf16x8 v = *(const bf16x8*)(qkv + (size_t)(b * T_ + t0 + row) * C3_ +
                                    src0 + seg * 8);
        *(bf16x8*)(tl + row * 64 + ((seg ^ (row & 7)) * 8)) = v;
    }
    __syncthreads();
#pragma unroll
    for (int c = 0; c < 2; ++c) {
        int i = tid + c * 256;
        int d = i >> 3, ts = i & 7;
        bf16x8 o;
#pragma unroll
        for (int j = 0; j < 8; ++j)
            o[j] = tl[(ts * 8 + j) * 64 + (d ^ (j * 8))];
        *(bf16x8*)(vt + (size_t)(hv * 64 + d) * T_ + t0 + ts * 8) = o;
    }
}

// ---------------------------------------------------------------------------
// Causal flash attention, swapped-QK^T. Depth-2 prefetch (3 buffers),
// raw s_barrier + counted vmcnt. Grid 768 flat, XCD-grouped per (b,h).
// ---------------------------------------------------------------------------
__global__ __launch_bounds__(256) void attn_kernel(const bf16* __restrict__ qkv,
                                                   const bf16* __restrict__ vt,
                                                   bf16* __restrict__ y) {
    const int flat = blockIdx.x;
    const int g = (flat & 7) * 6 + (flat >> 3) / 16;  // 0..47 = b*H+h
    const int qt = (flat >> 3) & 15;
    const int h = g % H_, b = g / H_, hv = g;

    const int tid = threadIdx.x, l = tid & 63, w = tid >> 6;
    const int lr = l & 15, lh = l >> 4, d0 = lh * 8;
    const int bc = h * 192;

    __shared__ bf16 Kl[3][64 * 64];
    __shared__ bf16 Vl[3][64 * 64];
    __shared__ bf16 Pl[4][16 * 64];

    const int qg = qt * 64 + w * 16 + lr;
    const bf16* qp = qkv + (size_t)(b * T_ + qg) * C3_ + bc;
    bf16x8 qf0 = *(const bf16x8*)(qp + d0);
    bf16x8 qf1 = *(const bf16x8*)(qp + 32 + d0);

    const int srow = tid >> 3;
    const int ss = (tid & 7) ^ (srow & 7);
    const bf16* k0p = qkv + (size_t)(b * T_ + srow) * C3_ + bc + 64 + ss * 8;
    const bf16* k1p = k0p + (size_t)32 * C3_;
    const bf16* v0p = vt + (size_t)(hv * 64 + srow) * T_ + ss * 8;
    const bf16* v1p = v0p + (size_t)32 * T_;

#define ATTN_STAGE(buf, kc)                                                    \
    {                                                                          \
        GLOAD_LDS16(k0p + (size_t)(kc) * 64 * C3_, &Kl[buf][tid * 8]);         \
        GLOAD_LDS16(v0p + (kc) * 64, &Vl[buf][tid * 8]);                       \
        GLOAD_LDS16(k1p + (size_t)(kc) * 64 * C3_, &Kl[buf][(tid + 256) * 8]); \
        GLOAD_LDS16(v1p + (kc) * 64, &Vl[buf][(tid + 256) * 8]);               \
    }

    f32x4 acc_o[4] = {};
    float m_run = -1e30f, l_run = 0.f;
    const float SCL = 0.125f * 1.44269504089f;  // 1/sqrt(HD) * log2(e)

    ATTN_STAGE(0, 0);
    if (qt >= 1) ATTN_STAGE(1, 1);

    int cur = 0, nxt = 2;
    for (int kc = 0; kc <= qt; ++kc) {
        if (kc + 2 <= qt) {
            ATTN_STAGE(nxt, kc + 2);
            asm volatile("s_waitcnt vmcnt(8)" ::: "memory");
        } else if (kc + 1 <= qt) {
            asm volatile("s_waitcnt vmcnt(4)" ::: "memory");
        } else {
            asm volatile("s_waitcnt vmcnt(0)" ::: "memory");
        }
        __builtin_amdgcn_s_barrier();  // K/V stage(kc) visible

        const bf16* Kb = Kl[cur];
        const bf16* Vb = Vl[cur];

        // S^T = K Q^T : lane holds S[k = kc*64+nt*16+lh*4+r][q = qg]
        f32x4 st[4];
#pragma unroll
        for (int nt = 0; nt < 4; ++nt) {
            int R = nt * 16 + lr;
            const bf16* kb = Kb + R * 64;
            bf16x8 k0 = *(const bf16x8*)(kb + (lh ^ (R & 7)) * 8);
            bf16x8 k1 = *(const bf16x8*)(kb + ((4 + lh) ^ (R & 7)) * 8);
            f32x4 a = {};
            a = mfma16(k0, qf0, a);
            st[nt] = mfma16(k1, qf1, a);
        }

        // softmax in log2 domain; lane owns q-row qg, 16 k-values
        const int diag = (kc == qt);
        float p[16], pmax = -1e30f;
#pragma unroll
        for (int nt = 0; nt < 4; ++nt)
#pragma unroll
            for (int r = 0; r < 4; ++r) {
                float v = st[nt][r] * SCL;
                if (diag) {
                    int kg = kc * 64 + nt * 16 + lh * 4 + r;
                    if (kg > qg) v = -1e38f;
                }
                p[nt * 4 + r] = v;
                pmax = fmaxf(pmax, v);
            }
        pmax = fmaxf(pmax, __shfl_xor(pmax, 16, 64));
        pmax = fmaxf(pmax, __shfl_xor(pmax, 32, 64));

        if (!__all(pmax - m_run <= 8.0f)) {  // defer-max (T13), THR=8 (log2)
            float mnew = fmaxf(m_run, pmax);
            float sc = exp2f(m_run - mnew);
            l_run *= sc;
            m_run = mnew;
#pragma unroll
            for (int r = 0; r < 4; ++r) {
                float sq = __shfl(sc, lh * 4 + r, 64);
#pragma unroll
                for (int nt = 0; nt < 4; ++nt) acc_o[nt][r] *= sq;
            }
        }

        float lsum = 0.f;
#pragma unroll
        for (int i = 0; i < 16; ++i) {
            p[i] = exp2f(p[i] - m_run);
            lsum += p[i];
        }
        lsum += __shfl_xor(lsum, 16, 64);
        lsum += __shfl_xor(lsum, 32, 64);
        l_run += lsum;

        // P -> Pl[q_local = lr][k], swizzled rows
        {
            char* pw = (char*)&Pl[w][0];
            int swz = (lr & 7) << 4;
#pragma unroll
            for (int nt = 0; nt < 4; ++nt)
#pragma unroll
                for (int rr = 0; rr < 2; ++rr) {
                    int kk = nt * 16 + lh * 4 + rr * 2;
                    bf16x2 pr = {(bf16)p[nt * 4 + rr * 2],
                                 (bf16)p[nt * 4 + rr * 2 + 1]};
                    *(bf16x2*)(pw + lr * 128 + ((kk * 2) ^ swz)) = pr;
                }
        }

        // PV: a-frag = Pl rows (q_local), b-frag = Vl rows (d)
        {
            const bf16* pb = &Pl[w][0] + lr * 64;
            bf16x8 pa0 = *(const bf16x8*)(pb + (lh ^ (lr & 7)) * 8);
            bf16x8 pa1 = *(const bf16x8*)(pb + ((4 + lh) ^ (lr & 7)) * 8);
#pragma unroll
            for (int nt = 0; nt < 4; ++nt) {
                int R = nt * 16 + lr;
                const bf16* vb = Vb + R * 64;
                bf16x8 v0 = *(const bf16x8*)(vb + (lh ^ (R & 7)) * 8);
                bf16x8 v1 = *(const bf16x8*)(vb + ((4 + lh) ^ (R & 7)) * 8);
                acc_o[nt] = mfma16(pa0, v0, acc_o[nt]);
                acc_o[nt] = mfma16(pa1, v1, acc_o[nt]);
            }
        }
        asm volatile("s_waitcnt lgkmcnt(0)" ::: "memory");
        __builtin_amdgcn_s_barrier();  // all reads of buf[cur] done

        cur = (cur == 2) ? 0 : cur + 1;
        nxt = (nxt == 2) ? 0 : nxt + 1;
    }

    float rl = 1.0f / l_run;
#pragma unroll
    for (int r = 0; r < 4; ++r) {
        float rq = __shfl(rl, lh * 4 + r, 64);
        int q = qt * 64 + w * 16 + lh * 4 + r;
#pragma unroll
        for (int nt = 0; nt < 4; ++nt)
            y[(size_t)(b * T_ + q) * C_ + h * 64 + nt * 16 + lr] =
                (bf16)(acc_o[nt][r] * rq);
    }
#undef ATTN_STAGE
}

// ---------------------------------------------------------------------------
extern "C" void kernel_launch(void* const* d_in, const int* in_sizes, int n_in,
                              void* d_out, int out_size, void* d_ws, size_t ws_size,
                              hipStream_t stream) {
    (void)in_sizes; (void)n_in; (void)out_size; (void)ws_size;
    const float* x     = (const float*)d_in[0];
    const float* ln1_s = (const float*)d_in[1];
    const float* ln1_b = (const float*)d_in[2];
    const float* Wqkv  = (const float*)d_in[3];
    const float* bqkv  = (const float*)d_in[4];
    const float* Wo    = (const float*)d_in[5];
    const float* bo    = (const float*)d_in[6];
    const float* ln2_s = (const float*)d_in[7];
    const float* ln2_b = (const float*)d_in[8];
    const float* Wfc   = (const float*)d_in[9];
    const float* bfc   = (const float*)d_in[10];
    const float* Wproj = (const float*)d_in[11];
    const float* bproj = (const float*)d_in[12];

    char* ws = (char*)d_ws;
    float* x2     = (float*)(ws);
    bf16*  vtbuf  = (bf16*)(ws);                      // aliases x2 (live: vtrans..attn)
    bf16*  fcbuf  = (bf16*)(ws + 12582912);
    bf16*  WprojT = (bf16*)(ws + 37748736);
    bf16*  lnbuf  = (bf16*)(ws + 42467328);
    float* parts  = (float*)(ws + 42467328);          // aliases lnbuf+qkv (live: proj..reduce)
    bf16*  qkv    = (bf16*)(ws + 48758784);
    bf16*  WqkvT  = (bf16*)(ws + 67633152);
    bf16*  WoT    = (bf16*)(ws + 71172096);
    bf16*  WfcT   = (bf16*)(ws + 72351744);

    dim3 tb(32, 8);
    transpose_cast_kernel<<<dim3(C3_ / 32, C_ / 32), tb, 0, stream>>>(Wqkv, WqkvT, C_, C3_);
    transpose_cast_kernel<<<dim3(C_ / 32, C_ / 32), tb, 0, stream>>>(Wo, WoT, C_, C_);
    transpose_cast_kernel<<<dim3(C4_ / 32, C_ / 32), tb, 0, stream>>>(Wfc, WfcT, C_, C4_);
    transpose_cast_kernel<<<dim3(C_ / 32, C4_ / 32), tb, 0, stream>>>(Wproj, WprojT, C4_, C_);

    ln_kernel<<<M_, 256, 0, stream>>>(x, ln1_s, ln1_b, lnbuf);

    // grids: (M/128) * (N/256) blocks, all divisible by 8, all co-resident
    gemm_kernel<EPI_BF16><<<dim3(288, 1), 256, 0, stream>>>(
        lnbuf, WqkvT, bqkv, nullptr, qkv, C3_, C_, 9);

    vtrans_kernel<<<dim3(T_ / 64, B_ * H_), 256, 0, stream>>>(qkv, vtbuf);

    attn_kernel<<<dim3(768), 256, 0, stream>>>(qkv, vtbuf, lnbuf);

    gemm_kernel<EPI_RES_F32><<<dim3(96, 1), 256, 0, stream>>>(
        lnbuf, WoT, bo, x, x2, C_, C_, 3);

    ln_kernel<<<M_, 256, 0, stream>>>(x2, ln2_s, ln2_b, lnbuf);

    gemm_kernel<EPI_GELU_BF16><<<dim3(384, 1), 256, 0, stream>>>(
        lnbuf, WfcT, bfc, nullptr, fcbuf, C4_, C_, 12);

    gemm_kernel<EPI_PARTIAL><<<dim3(96, 2), 256, 0, stream>>>(
        fcbuf, WprojT, nullptr, nullptr, parts, C_, C4_, 3);

    reduce2_kernel<<<dim3((M_ * C_) / 1024), 256, 0, stream>>>(parts, bproj, x2,
                                                               (float*)d_out);
}

// Round 9
// 187.220 us; speedup vs baseline: 1.3485x; 1.1935x over previous
//
#include <hip/hip_runtime.h>
#include <hip/hip_bf16.h>
#include <math.h>

#define B_  4
#define T_  1024
#define C_  768
#define H_  12
#define HD_ 64
#define M_  (B_*T_)     // 4096 rows
#define C3_ (3*C_)      // 2304
#define C4_ (4*C_)      // 3072

typedef __bf16 bf16;
typedef bf16  bf16x2 __attribute__((ext_vector_type(2)));
typedef bf16  bf16x8 __attribute__((ext_vector_type(8)));
typedef float f32x4  __attribute__((ext_vector_type(4)));

__device__ __forceinline__ f32x4 mfma16(bf16x8 a, bf16x8 b, f32x4 c) {
    return __builtin_amdgcn_mfma_f32_16x16x32_bf16(a, b, c, 0, 0, 0);
}

#define GLOAD_LDS16(g, l)                                                     \
    __builtin_amdgcn_global_load_lds(                                         \
        (const __attribute__((address_space(1))) void*)(g),                   \
        (__attribute__((address_space(3))) void*)(l), 16, 0, 0)

// ---------------------------------------------------------------------------
// Merged transpose+cast for all 4 weights: fp32 [K,N] -> bf16 [N,K].
// Flat grid of 32x32 tiles; range decode selects the matrix.
// ---------------------------------------------------------------------------
__global__ void tcast_all_kernel(const float* __restrict__ Wqkv,
                                 const float* __restrict__ Wo,
                                 const float* __restrict__ Wfc,
                                 const float* __restrict__ Wproj,
                                 bf16* __restrict__ WqkvT, bf16* __restrict__ WoT,
                                 bf16* __restrict__ WfcT, bf16* __restrict__ WprojT) {
    __shared__ float tile[32][33];
    const int id = blockIdx.x;
    const float* in; bf16* out; int K, N, local;
    if (id < 1728)      { in = Wqkv;  out = WqkvT;  K = 768;  N = 2304; local = id; }
    else if (id < 2304) { in = Wo;    out = WoT;    K = 768;  N = 768;  local = id - 1728; }
    else if (id < 4608) { in = Wfc;   out = WfcT;   K = 768;  N = 3072; local = id - 2304; }
    else                { in = Wproj; out = WprojT; K = 3072; N = 768;  local = id - 4608; }
    const int tn = N >> 5;
    const int n0 = (local % tn) * 32, k0 = (local / tn) * 32;
    const int tx = threadIdx.x, ty = threadIdx.y;  // 32 x 8
#pragma unroll
    for (int i = 0; i < 32; i += 8)
        tile[ty + i][tx] = in[(size_t)(k0 + ty + i) * N + n0 + tx];
    __syncthreads();
#pragma unroll
    for (int i = 0; i < 32; i += 8)
        out[(size_t)(n0 + ty + i) * K + k0 + tx] = (bf16)tile[tx][ty + i];
}

// ---------------------------------------------------------------------------
// LayerNorm: fp32 in [rows, 768] -> bf16 out. One block (256 thr) per row.
// ---------------------------------------------------------------------------
__device__ __forceinline__ float block_sum256(float v, float* red, int tid) {
#pragma unroll
    for (int m = 32; m >= 1; m >>= 1) v += __shfl_xor(v, m, 64);
    if ((tid & 63) == 0) red[tid >> 6] = v;
    __syncthreads();
    v = red[0] + red[1] + red[2] + red[3];
    __syncthreads();
    return v;
}

__global__ __launch_bounds__(256) void ln_kernel(const float* __restrict__ in,
                                                 const float* __restrict__ scale,
                                                 const float* __restrict__ bias,
                                                 bf16* __restrict__ out) {
    __shared__ float red[4];
    int row = blockIdx.x, tid = threadIdx.x;
    const float* p = in + (size_t)row * C_;
    float v0 = p[tid], v1 = p[tid + 256], v2 = p[tid + 512];
    float mu = block_sum256(v0 + v1 + v2, red, tid) * (1.0f / C_);
    float d0 = v0 - mu, d1 = v1 - mu, d2 = v2 - mu;
    float var = block_sum256(d0 * d0 + d1 * d1 + d2 * d2, red, tid) * (1.0f / C_);
    float rstd = rsqrtf(var + 1e-5f);
    bf16* o = out + (size_t)row * C_;
    o[tid]       = (bf16)(d0 * rstd * scale[tid]       + bias[tid]);
    o[tid + 256] = (bf16)(d1 * rstd * scale[tid + 256] + bias[tid + 256]);
    o[tid + 512] = (bf16)(d2 * rstd * scale[tid + 512] + bias[tid + 512]);
}

// ---------------------------------------------------------------------------
// GEMM (round-4 proven structure): C[M,N] = A[M,K] * BT[N,K]^T (+epilogue).
// BM = MT*32 (MT=4 -> 128x128, wave 64x64; MT=2 -> 64x128, wave 32x64),
// BN=128, BK=32, 4 waves (2x2). 3 LDS buffers, depth-2 prefetch, counted
// vmcnt (never 0 in-loop), swizzle c^((row>>1)&3) (measured 0 conflicts).
// MT=2: 36 KB LDS + light VGPR -> ~4 blocks/CU for grid-starved N=768 GEMMs.
// Grid MUST be (M/BM)*(N/128) blocks (round-8 bug: fc launched with half).
// ---------------------------------------------------------------------------
enum { EPI_BF16 = 0, EPI_RES_F32 = 1, EPI_GELU_BF16 = 2 };

template <int EPI, int MT>
__global__ __launch_bounds__(256) void gemm_kernel(
    const bf16* __restrict__ A, const bf16* __restrict__ BT,
    const float* __restrict__ bias, const float* __restrict__ res,
    void* __restrict__ outv, int N, int Ktot, int nx) {
    constexpr int BM = MT * 32;
    __shared__ bf16 Al[3][BM * 32];
    __shared__ bf16 Bl[3][128 * 32];
    const int tid = threadIdx.x;
    const int l = tid & 63, w = tid >> 6;
    const int wm = w >> 1, wn = w & 1;
    // bijective XCD-chunked swizzle (gridDim.x divisible by 8)
    const int cpx = gridDim.x >> 3;
    const int wg = (blockIdx.x & 7) * cpx + (blockIdx.x >> 3);
    const int bm = (wg / nx) * BM, bn = (wg % nx) * 128;
    const int Kper = Ktot / gridDim.y;
    const int k0 = blockIdx.y * Kper;
    const int lr = l & 15, lh = l >> 4;

    // staging: LDS chunk (row, c) holds global k-chunk c ^ ((row>>1)&3);
    // thread tid covers rows {srow (+64)}; xor term invariant across +64.
    const int srow = tid >> 2;
    const int scol = ((tid & 3) ^ ((srow >> 1) & 3)) * 8;
    const bf16* gA = A + (size_t)(bm + srow) * Ktot + k0 + scol;
    const bf16* gB = BT + (size_t)(bn + srow) * Ktot + k0 + scol;

// koff = K offset in ELEMENTS within this block's K-slice.
// loads/stage: MT=4 -> 4, MT=2 -> 3.
#define GEMM_STAGE(buf, koff)                                                  \
    {                                                                          \
        GLOAD_LDS16(gA + (koff), &Al[buf][tid * 8]);                           \
        if (MT == 4)                                                           \
            GLOAD_LDS16(gA + (size_t)64 * Ktot + (koff),                       \
                        &Al[buf][(tid + 256) * 8]);                            \
        GLOAD_LDS16(gB + (koff), &Bl[buf][tid * 8]);                           \
        GLOAD_LDS16(gB + (size_t)64 * Ktot + (koff),                           \
                    &Bl[buf][(tid + 256) * 8]);                                \
    }

    // read-side swizzled chunk offset (elements) within a 32-elem row
    const int rdoff = (lh ^ ((lr >> 1) & 3)) * 8;

    f32x4 acc[MT][4] = {};
    const int nk = Kper >> 5;

    GEMM_STAGE(0, 0);
    GEMM_STAGE(1, 32);
    if (MT == 4) asm volatile("s_waitcnt vmcnt(4)" ::: "memory");
    else         asm volatile("s_waitcnt vmcnt(3)" ::: "memory");
    __builtin_amdgcn_s_barrier();

    int cur = 0, sb = 2;
    for (int t = 0; t < nk; ++t) {
        if (t + 2 < nk) {
            GEMM_STAGE(sb, (t + 2) * 32);
            if (MT == 4) asm volatile("s_waitcnt vmcnt(8)" ::: "memory");
            else         asm volatile("s_waitcnt vmcnt(6)" ::: "memory");
        } else if (t + 1 < nk) {
            if (MT == 4) asm volatile("s_waitcnt vmcnt(4)" ::: "memory");
            else         asm volatile("s_waitcnt vmcnt(3)" ::: "memory");
        } else {
            asm volatile("s_waitcnt vmcnt(0)" ::: "memory");
        }
        __builtin_amdgcn_s_barrier();  // stage(t) visible to all waves

        bf16x8 af[MT], bfr[4];
#pragma unroll
        for (int mt = 0; mt < MT; ++mt)
            af[mt] = *(const bf16x8*)(&Al[cur][(wm * (MT * 16) + mt * 16 + lr) * 32 + rdoff]);
#pragma unroll
        for (int nt = 0; nt < 4; ++nt)
            bfr[nt] = *(const bf16x8*)(&Bl[cur][(wn * 64 + nt * 16 + lr) * 32 + rdoff]);
        asm volatile("s_waitcnt lgkmcnt(0)" ::: "memory");
        __builtin_amdgcn_s_barrier();  // all reads of buf[cur] done

#pragma unroll
        for (int mt = 0; mt < MT; ++mt)
#pragma unroll
            for (int nt = 0; nt < 4; ++nt)
                acc[mt][nt] = mfma16(af[mt], bfr[nt], acc[mt][nt]);

        cur = (cur == 2) ? 0 : cur + 1;
        sb = (sb == 2) ? 0 : sb + 1;
    }
#undef GEMM_STAGE

#pragma unroll
    for (int mt = 0; mt < MT; ++mt) {
#pragma unroll
        for (int nt = 0; nt < 4; ++nt) {
#pragma unroll
            for (int r = 0; r < 4; ++r) {
                int row = bm + wm * (MT * 16) + mt * 16 + lh * 4 + r;
                int col = bn + wn * 64 + nt * 16 + lr;
                float v = acc[mt][nt][r] + bias[col];
                if (EPI == EPI_RES_F32) {
                    ((float*)outv)[(size_t)row * N + col] =
                        v + res[(size_t)row * N + col];
                } else if (EPI == EPI_GELU_BF16) {
                    // faithful to source: tanh(z), z = sqrt(2/pi)*0.044715*x^4
                    // tanh form: g = v - v/(e^{2z}+1); z>=0, inf-safe.
                    float x4 = v * v * v * v;
                    float e = __expf(0.07135494f * x4);  // e^{2z}
                    float g = v - v / (e + 1.0f);
                    ((bf16*)outv)[(size_t)row * N + col] = (bf16)g;
                } else {
                    ((bf16*)outv)[(size_t)row * N + col] = (bf16)v;
                }
            }
        }
    }
}

// ---------------------------------------------------------------------------
// V pre-transpose: qkv V-part [t][d] per head -> vt[(b*H+h)][d=64][T=1024]
// ---------------------------------------------------------------------------
__global__ __launch_bounds__(256) void vtrans_kernel(const bf16* __restrict__ qkv,
                                                     bf16* __restrict__ vt) {
    __shared__ bf16 tl[64 * 64];
    const int tid = threadIdx.x;
    const int t0 = blockIdx.x * 64;
    const int hv = blockIdx.y;          // b*H + h
    const int b = hv / H_, h = hv % H_;
    const int src0 = h * 192 + 128;
#pragma unroll
    for (int c = 0; c < 2; ++c) {
        int i = tid + c * 256;
        int row = i >> 3, seg = i & 7;  // row = t-within-tile
        bf16x8 v = *(const bf16x8*)(qkv + (size_t)(b * T_ + t0 + row) * C3_ +
                                    src0 + seg * 8);
        *(bf16x8*)(tl + row * 64 + ((seg ^ (row & 7)) * 8)) = v;
    }
    __syncthreads();
#pragma unroll
    for (int c = 0; c < 2; ++c) {
        int i = tid + c * 256;
        int d = i >> 3, ts = i & 7;
        bf16x8 o;
#pragma unroll
        for (int j = 0; j < 8; ++j)
            o[j] = tl[(ts * 8 + j) * 64 + (d ^ (j * 8))];
        *(bf16x8*)(vt + (size_t)(hv * 64 + d) * T_ + t0 + ts * 8) = o;
    }
}

// ---------------------------------------------------------------------------
// Causal flash attention, swapped-QK^T. Depth-2 prefetch (3 buffers),
// raw s_barrier + counted vmcnt. Grid 768 flat, XCD-grouped per (b,h).
// ---------------------------------------------------------------------------
__global__ __launch_bounds__(256) void attn_kernel(const bf16* __restrict__ qkv,
                                                   const bf16* __restrict__ vt,
                                                   bf16* __restrict__ y) {
    const int flat = blockIdx.x;
    const int g = (flat & 7) * 6 + (flat >> 3) / 16;  // 0..47 = b*H+h
    const int qt = (flat >> 3) & 15;
    const int h = g % H_, b = g / H_, hv = g;

    const int tid = threadIdx.x, l = tid & 63, w = tid >> 6;
    const int lr = l & 15, lh = l >> 4, d0 = lh * 8;
    const int bc = h * 192;

    __shared__ bf16 Kl[3][64 * 64];
    __shared__ bf16 Vl[3][64 * 64];
    __shared__ bf16 Pl[4][16 * 64];

    const int qg = qt * 64 + w * 16 + lr;
    const bf16* qp = qkv + (size_t)(b * T_ + qg) * C3_ + bc;
    bf16x8 qf0 = *(const bf16x8*)(qp + d0);
    bf16x8 qf1 = *(const bf16x8*)(qp + 32 + d0);

    const int srow = tid >> 3;
    const int ss = (tid & 7) ^ (srow & 7);
    const bf16* k0p = qkv + (size_t)(b * T_ + srow) * C3_ + bc + 64 + ss * 8;
    const bf16* k1p = k0p + (size_t)32 * C3_;
    const bf16* v0p = vt + (size_t)(hv * 64 + srow) * T_ + ss * 8;
    const bf16* v1p = v0p + (size_t)32 * T_;

#define ATTN_STAGE(buf, kc)                                                    \
    {                                                                          \
        GLOAD_LDS16(k0p + (size_t)(kc) * 64 * C3_, &Kl[buf][tid * 8]);         \
        GLOAD_LDS16(v0p + (kc) * 64, &Vl[buf][tid * 8]);                       \
        GLOAD_LDS16(k1p + (size_t)(kc) * 64 * C3_, &Kl[buf][(tid + 256) * 8]); \
        GLOAD_LDS16(v1p + (kc) * 64, &Vl[buf][(tid + 256) * 8]);               \
    }

    f32x4 acc_o[4] = {};
    float m_run = -1e30f, l_run = 0.f;
    const float SCL = 0.125f * 1.44269504089f;  // 1/sqrt(HD) * log2(e)

    ATTN_STAGE(0, 0);
    if (qt >= 1) ATTN_STAGE(1, 1);

    int cur = 0, nxt = 2;
    for (int kc = 0; kc <= qt; ++kc) {
        if (kc + 2 <= qt) {
            ATTN_STAGE(nxt, kc + 2);
            asm volatile("s_waitcnt vmcnt(8)" ::: "memory");
        } else if (kc + 1 <= qt) {
            asm volatile("s_waitcnt vmcnt(4)" ::: "memory");
        } else {
            asm volatile("s_waitcnt vmcnt(0)" ::: "memory");
        }
        __builtin_amdgcn_s_barrier();  // K/V stage(kc) visible

        const bf16* Kb = Kl[cur];
        const bf16* Vb = Vl[cur];

        // S^T = K Q^T : lane holds S[k = kc*64+nt*16+lh*4+r][q = qg]
        f32x4 st[4];
#pragma unroll
        for (int nt = 0; nt < 4; ++nt) {
            int R = nt * 16 + lr;
            const bf16* kb = Kb + R * 64;
            bf16x8 k0 = *(const bf16x8*)(kb + (lh ^ (R & 7)) * 8);
            bf16x8 k1 = *(const bf16x8*)(kb + ((4 + lh) ^ (R & 7)) * 8);
            f32x4 a = {};
            a = mfma16(k0, qf0, a);
            st[nt] = mfma16(k1, qf1, a);
        }

        // softmax in log2 domain; lane owns q-row qg, 16 k-values
        const int diag = (kc == qt);
        float p[16], pmax = -1e30f;
#pragma unroll
        for (int nt = 0; nt < 4; ++nt)
#pragma unroll
            for (int r = 0; r < 4; ++r) {
                float v = st[nt][r] * SCL;
                if (diag) {
                    int kg = kc * 64 + nt * 16 + lh * 4 + r;
                    if (kg > qg) v = -1e38f;
                }
                p[nt * 4 + r] = v;
                pmax = fmaxf(pmax, v);
            }
        pmax = fmaxf(pmax, __shfl_xor(pmax, 16, 64));
        pmax = fmaxf(pmax, __shfl_xor(pmax, 32, 64));

        if (!__all(pmax - m_run <= 8.0f)) {  // defer-max (T13), THR=8 (log2)
            float mnew = fmaxf(m_run, pmax);
            float sc = exp2f(m_run - mnew);
            l_run *= sc;
            m_run = mnew;
#pragma unroll
            for (int r = 0; r < 4; ++r) {
                float sq = __shfl(sc, lh * 4 + r, 64);
#pragma unroll
                for (int nt = 0; nt < 4; ++nt) acc_o[nt][r] *= sq;
            }
        }

        float lsum = 0.f;
#pragma unroll
        for (int i = 0; i < 16; ++i) {
            p[i] = exp2f(p[i] - m_run);
            lsum += p[i];
        }
        lsum += __shfl_xor(lsum, 16, 64);
        lsum += __shfl_xor(lsum, 32, 64);
        l_run += lsum;

        // P -> Pl[q_local = lr][k], swizzled rows
        {
            char* pw = (char*)&Pl[w][0];
            int swz = (lr & 7) << 4;
#pragma unroll
            for (int nt = 0; nt < 4; ++nt)
#pragma unroll
                for (int rr = 0; rr < 2; ++rr) {
                    int kk = nt * 16 + lh * 4 + rr * 2;
                    bf16x2 pr = {(bf16)p[nt * 4 + rr * 2],
                                 (bf16)p[nt * 4 + rr * 2 + 1]};
                    *(bf16x2*)(pw + lr * 128 + ((kk * 2) ^ swz)) = pr;
                }
        }

        // PV: a-frag = Pl rows (q_local), b-frag = Vl rows (d)
        {
            const bf16* pb = &Pl[w][0] + lr * 64;
            bf16x8 pa0 = *(const bf16x8*)(pb + (lh ^ (lr & 7)) * 8);
            bf16x8 pa1 = *(const bf16x8*)(pb + ((4 + lh) ^ (lr & 7)) * 8);
#pragma unroll
            for (int nt = 0; nt < 4; ++nt) {
                int R = nt * 16 + lr;
                const bf16* vb = Vb + R * 64;
                bf16x8 v0 = *(const bf16x8*)(vb + (lh ^ (R & 7)) * 8);
                bf16x8 v1 = *(const bf16x8*)(vb + ((4 + lh) ^ (R & 7)) * 8);
                acc_o[nt] = mfma16(pa0, v0, acc_o[nt]);
                acc_o[nt] = mfma16(pa1, v1, acc_o[nt]);
            }
        }
        asm volatile("s_waitcnt lgkmcnt(0)" ::: "memory");
        __builtin_amdgcn_s_barrier();  // all reads of buf[cur] done

        cur = (cur == 2) ? 0 : cur + 1;
        nxt = (nxt == 2) ? 0 : nxt + 1;
    }

    float rl = 1.0f / l_run;
#pragma unroll
    for (int r = 0; r < 4; ++r) {
        float rq = __shfl(rl, lh * 4 + r, 64);
        int q = qt * 64 + w * 16 + lh * 4 + r;
#pragma unroll
        for (int nt = 0; nt < 4; ++nt)
            y[(size_t)(b * T_ + q) * C_ + h * 64 + nt * 16 + lr] =
                (bf16)(acc_o[nt][r] * rq);
    }
#undef ATTN_STAGE
}

// ---------------------------------------------------------------------------
extern "C" void kernel_launch(void* const* d_in, const int* in_sizes, int n_in,
                              void* d_out, int out_size, void* d_ws, size_t ws_size,
                              hipStream_t stream) {
    (void)in_sizes; (void)n_in; (void)out_size; (void)ws_size;
    const float* x     = (const float*)d_in[0];
    const float* ln1_s = (const float*)d_in[1];
    const float* ln1_b = (const float*)d_in[2];
    const float* Wqkv  = (const float*)d_in[3];
    const float* bqkv  = (const float*)d_in[4];
    const float* Wo    = (const float*)d_in[5];
    const float* bo    = (const float*)d_in[6];
    const float* ln2_s = (const float*)d_in[7];
    const float* ln2_b = (const float*)d_in[8];
    const float* Wfc   = (const float*)d_in[9];
    const float* bfc   = (const float*)d_in[10];
    const float* Wproj = (const float*)d_in[11];
    const float* bproj = (const float*)d_in[12];

    char* ws = (char*)d_ws;
    float* x2     = (float*)(ws);
    bf16*  vtbuf  = (bf16*)(ws);                      // aliases x2 (live: vtrans..attn)
    bf16*  fcbuf  = (bf16*)(ws + 12582912);
    bf16*  WprojT = (bf16*)(ws + 37748736);
    bf16*  lnbuf  = (bf16*)(ws + 42467328);
    bf16*  qkv    = (bf16*)(ws + 48758784);
    bf16*  WqkvT  = (bf16*)(ws + 67633152);
    bf16*  WoT    = (bf16*)(ws + 71172096);
    bf16*  WfcT   = (bf16*)(ws + 72351744);

    tcast_all_kernel<<<dim3(6912), dim3(32, 8), 0, stream>>>(
        Wqkv, Wo, Wfc, Wproj, WqkvT, WoT, WfcT, WprojT);

    ln_kernel<<<M_, 256, 0, stream>>>(x, ln1_s, ln1_b, lnbuf);

    gemm_kernel<EPI_BF16, 4><<<dim3(576, 1), 256, 0, stream>>>(
        lnbuf, WqkvT, bqkv, nullptr, qkv, C3_, C_, 18);

    vtrans_kernel<<<dim3(T_ / 64, B_ * H_), 256, 0, stream>>>(qkv, vtbuf);

    attn_kernel<<<dim3(768), 256, 0, stream>>>(qkv, vtbuf, lnbuf);

    // N=768 GEMMs: BM=64 -> grid 384 (vs 192 at BM=128), 4 blocks/CU
    gemm_kernel<EPI_RES_F32, 2><<<dim3(384, 1), 256, 0, stream>>>(
        lnbuf, WoT, bo, x, x2, C_, C_, 6);

    ln_kernel<<<M_, 256, 0, stream>>>(x2, ln2_s, ln2_b, lnbuf);

    // fc: 32 M-tiles x 24 N-tiles = 768 blocks (round-8 bug: was 384)
    gemm_kernel<EPI_GELU_BF16, 4><<<dim3(768, 1), 256, 0, stream>>>(
        lnbuf, WfcT, bfc, nullptr, fcbuf, C4_, C_, 24);

    // proj direct (no split-K): grid 384 at BM=64, K=3072
    gemm_kernel<EPI_RES_F32, 2><<<dim3(384, 1), 256, 0, stream>>>(
        fcbuf, WprojT, bproj, x2, (float*)d_out, C_, C4_, 6);
}

// Round 10
// 181.915 us; speedup vs baseline: 1.3878x; 1.0292x over previous
//
#include <hip/hip_runtime.h>
#include <hip/hip_bf16.h>
#include <math.h>

#define B_  4
#define T_  1024
#define C_  768
#define H_  12
#define HD_ 64
#define M_  (B_*T_)     // 4096 rows
#define C3_ (3*C_)      // 2304
#define C4_ (4*C_)      // 3072

typedef __bf16 bf16;
typedef bf16  bf16x2 __attribute__((ext_vector_type(2)));
typedef bf16  bf16x8 __attribute__((ext_vector_type(8)));
typedef float f32x4  __attribute__((ext_vector_type(4)));

__device__ __forceinline__ f32x4 mfma16(bf16x8 a, bf16x8 b, f32x4 c) {
    return __builtin_amdgcn_mfma_f32_16x16x32_bf16(a, b, c, 0, 0, 0);
}

#define GLOAD_LDS16(g, l)                                                     \
    __builtin_amdgcn_global_load_lds(                                         \
        (const __attribute__((address_space(1))) void*)(g),                   \
        (__attribute__((address_space(3))) void*)(l), 16, 0, 0)

// ---------------------------------------------------------------------------
// Merged transpose+cast for all 4 weights: fp32 [K,N] -> bf16 [N,K].
// ---------------------------------------------------------------------------
__global__ void tcast_all_kernel(const float* __restrict__ Wqkv,
                                 const float* __restrict__ Wo,
                                 const float* __restrict__ Wfc,
                                 const float* __restrict__ Wproj,
                                 bf16* __restrict__ WqkvT, bf16* __restrict__ WoT,
                                 bf16* __restrict__ WfcT, bf16* __restrict__ WprojT) {
    __shared__ float tile[32][33];
    const int id = blockIdx.x;
    const float* in; bf16* out; int K, N, local;
    if (id < 1728)      { in = Wqkv;  out = WqkvT;  K = 768;  N = 2304; local = id; }
    else if (id < 2304) { in = Wo;    out = WoT;    K = 768;  N = 768;  local = id - 1728; }
    else if (id < 4608) { in = Wfc;   out = WfcT;   K = 768;  N = 3072; local = id - 2304; }
    else                { in = Wproj; out = WprojT; K = 3072; N = 768;  local = id - 4608; }
    const int tn = N >> 5;
    const int n0 = (local % tn) * 32, k0 = (local / tn) * 32;
    const int tx = threadIdx.x, ty = threadIdx.y;  // 32 x 8
#pragma unroll
    for (int i = 0; i < 32; i += 8)
        tile[ty + i][tx] = in[(size_t)(k0 + ty + i) * N + n0 + tx];
    __syncthreads();
#pragma unroll
    for (int i = 0; i < 32; i += 8)
        out[(size_t)(n0 + ty + i) * K + k0 + tx] = (bf16)tile[tx][ty + i];
}

// ---------------------------------------------------------------------------
// LayerNorm: fp32 in [rows, 768] -> bf16 out. One block (256 thr) per row.
// ---------------------------------------------------------------------------
__device__ __forceinline__ float block_sum256(float v, float* red, int tid) {
#pragma unroll
    for (int m = 32; m >= 1; m >>= 1) v += __shfl_xor(v, m, 64);
    if ((tid & 63) == 0) red[tid >> 6] = v;
    __syncthreads();
    v = red[0] + red[1] + red[2] + red[3];
    __syncthreads();
    return v;
}

__global__ __launch_bounds__(256) void ln_kernel(const float* __restrict__ in,
                                                 const float* __restrict__ scale,
                                                 const float* __restrict__ bias,
                                                 bf16* __restrict__ out) {
    __shared__ float red[4];
    int row = blockIdx.x, tid = threadIdx.x;
    const float* p = in + (size_t)row * C_;
    float v0 = p[tid], v1 = p[tid + 256], v2 = p[tid + 512];
    float mu = block_sum256(v0 + v1 + v2, red, tid) * (1.0f / C_);
    float d0 = v0 - mu, d1 = v1 - mu, d2 = v2 - mu;
    float var = block_sum256(d0 * d0 + d1 * d1 + d2 * d2, red, tid) * (1.0f / C_);
    float rstd = rsqrtf(var + 1e-5f);
    bf16* o = out + (size_t)row * C_;
    o[tid]       = (bf16)(d0 * rstd * scale[tid]       + bias[tid]);
    o[tid + 256] = (bf16)(d1 * rstd * scale[tid + 256] + bias[tid + 256]);
    o[tid + 512] = (bf16)(d2 * rstd * scale[tid + 512] + bias[tid + 512]);
}

// ---------------------------------------------------------------------------
// GEMM (round-4 proven structure): C[M,N] = A[M,K] * BT[N,K]^T (+epilogue).
// BM = MT*32, BN=128, BK=32, 4 waves (2x2). 3 LDS buffers, depth-2 prefetch,
// counted vmcnt (never 0 in-loop), swizzle c^((row>>1)&3) (0 conflicts).
// MT=4 (128^2, 16 MFMA/wave/step) is the strong config; MT=2 only for
// grid-starved short-K GEMMs (wo). Long-K N=768 (proj) uses MT=4 + split-K=2
// (round-9 measured: proj at MT=2 no-split = 52us, worse than split-K ~35).
// ---------------------------------------------------------------------------
enum { EPI_BF16 = 0, EPI_RES_F32 = 1, EPI_GELU_BF16 = 2, EPI_PARTIAL = 3 };

template <int EPI, int MT>
__global__ __launch_bounds__(256) void gemm_kernel(
    const bf16* __restrict__ A, const bf16* __restrict__ BT,
    const float* __restrict__ bias, const float* __restrict__ res,
    void* __restrict__ outv, int N, int Ktot, int nx) {
    constexpr int BM = MT * 32;
    __shared__ bf16 Al[3][BM * 32];
    __shared__ bf16 Bl[3][128 * 32];
    const int tid = threadIdx.x;
    const int l = tid & 63, w = tid >> 6;
    const int wm = w >> 1, wn = w & 1;
    // bijective XCD-chunked swizzle (gridDim.x divisible by 8)
    const int cpx = gridDim.x >> 3;
    const int wg = (blockIdx.x & 7) * cpx + (blockIdx.x >> 3);
    const int bm = (wg / nx) * BM, bn = (wg % nx) * 128;
    const int Kper = Ktot / gridDim.y;
    const int k0 = blockIdx.y * Kper;
    const int lr = l & 15, lh = l >> 4;

    // staging: LDS chunk (row, c) holds global k-chunk c ^ ((row>>1)&3);
    // thread tid covers rows {srow (+64)}; xor term invariant across +64.
    const int srow = tid >> 2;
    const int scol = ((tid & 3) ^ ((srow >> 1) & 3)) * 8;
    const bf16* gA = A + (size_t)(bm + srow) * Ktot + k0 + scol;
    const bf16* gB = BT + (size_t)(bn + srow) * Ktot + k0 + scol;

// koff = K offset in ELEMENTS within this block's K-slice.
#define GEMM_STAGE(buf, koff)                                                  \
    {                                                                          \
        GLOAD_LDS16(gA + (koff), &Al[buf][tid * 8]);                           \
        if (MT == 4)                                                           \
            GLOAD_LDS16(gA + (size_t)64 * Ktot + (koff),                       \
                        &Al[buf][(tid + 256) * 8]);                            \
        GLOAD_LDS16(gB + (koff), &Bl[buf][tid * 8]);                           \
        GLOAD_LDS16(gB + (size_t)64 * Ktot + (koff),                           \
                    &Bl[buf][(tid + 256) * 8]);                                \
    }

    // read-side swizzled chunk offset (elements) within a 32-elem row
    const int rdoff = (lh ^ ((lr >> 1) & 3)) * 8;

    f32x4 acc[MT][4] = {};
    const int nk = Kper >> 5;

    GEMM_STAGE(0, 0);
    GEMM_STAGE(1, 32);
    if (MT == 4) asm volatile("s_waitcnt vmcnt(4)" ::: "memory");
    else         asm volatile("s_waitcnt vmcnt(3)" ::: "memory");
    __builtin_amdgcn_s_barrier();

    int cur = 0, sb = 2;
    for (int t = 0; t < nk; ++t) {
        if (t + 2 < nk) {
            GEMM_STAGE(sb, (t + 2) * 32);
            if (MT == 4) asm volatile("s_waitcnt vmcnt(8)" ::: "memory");
            else         asm volatile("s_waitcnt vmcnt(6)" ::: "memory");
        } else if (t + 1 < nk) {
            if (MT == 4) asm volatile("s_waitcnt vmcnt(4)" ::: "memory");
            else         asm volatile("s_waitcnt vmcnt(3)" ::: "memory");
        } else {
            asm volatile("s_waitcnt vmcnt(0)" ::: "memory");
        }
        __builtin_amdgcn_s_barrier();  // stage(t) visible to all waves

        bf16x8 af[MT], bfr[4];
#pragma unroll
        for (int mt = 0; mt < MT; ++mt)
            af[mt] = *(const bf16x8*)(&Al[cur][(wm * (MT * 16) + mt * 16 + lr) * 32 + rdoff]);
#pragma unroll
        for (int nt = 0; nt < 4; ++nt)
            bfr[nt] = *(const bf16x8*)(&Bl[cur][(wn * 64 + nt * 16 + lr) * 32 + rdoff]);
        asm volatile("s_waitcnt lgkmcnt(0)" ::: "memory");
        __builtin_amdgcn_s_barrier();  // all reads of buf[cur] done

#pragma unroll
        for (int mt = 0; mt < MT; ++mt)
#pragma unroll
            for (int nt = 0; nt < 4; ++nt)
                acc[mt][nt] = mfma16(af[mt], bfr[nt], acc[mt][nt]);

        cur = (cur == 2) ? 0 : cur + 1;
        sb = (sb == 2) ? 0 : sb + 1;
    }
#undef GEMM_STAGE

#pragma unroll
    for (int mt = 0; mt < MT; ++mt) {
#pragma unroll
        for (int nt = 0; nt < 4; ++nt) {
#pragma unroll
            for (int r = 0; r < 4; ++r) {
                int row = bm + wm * (MT * 16) + mt * 16 + lh * 4 + r;
                int col = bn + wn * 64 + nt * 16 + lr;
                if (EPI == EPI_PARTIAL) {
                    ((float*)outv)[(size_t)blockIdx.y * M_ * N +
                                   (size_t)row * N + col] = acc[mt][nt][r];
                } else {
                    float v = acc[mt][nt][r] + bias[col];
                    if (EPI == EPI_RES_F32) {
                        ((float*)outv)[(size_t)row * N + col] =
                            v + res[(size_t)row * N + col];
                    } else if (EPI == EPI_GELU_BF16) {
                        // faithful: tanh(z), z = sqrt(2/pi)*0.044715*x^4
                        // g = v - v/(e^{2z}+1); z>=0, inf-safe.
                        float x4 = v * v * v * v;
                        float e = __expf(0.07135494f * x4);  // e^{2z}
                        float g = v - v / (e + 1.0f);
                        ((bf16*)outv)[(size_t)row * N + col] = (bf16)g;
                    } else {
                        ((bf16*)outv)[(size_t)row * N + col] = (bf16)v;
                    }
                }
            }
        }
    }
}

// ---------------------------------------------------------------------------
// Split-K=2 reduce: out = part0 + part1 + bias + res   (fp32, float4)
// ---------------------------------------------------------------------------
__global__ __launch_bounds__(256) void reduce2_kernel(const float* __restrict__ part,
                                                      const float* __restrict__ bias,
                                                      const float* __restrict__ res,
                                                      float* __restrict__ out) {
    const size_t MN = (size_t)M_ * C_;
    size_t i = ((size_t)blockIdx.x * 256 + threadIdx.x) * 4;
    if (i >= MN) return;
    f32x4 a = *(const f32x4*)(part + i);
    f32x4 b = *(const f32x4*)(part + MN + i);
    f32x4 r = *(const f32x4*)(res + i);
    f32x4 bi = *(const f32x4*)(bias + (int)(i % C_));
    *(f32x4*)(out + i) = a + b + r + bi;
}

// ---------------------------------------------------------------------------
// V pre-transpose: qkv V-part [t][d] per head -> vt[(b*H+h)][d=64][T=1024]
// ---------------------------------------------------------------------------
__global__ __launch_bounds__(256) void vtrans_kernel(const bf16* __restrict__ qkv,
                                                     bf16* __restrict__ vt) {
    __shared__ bf16 tl[64 * 64];
    const int tid = threadIdx.x;
    const int t0 = blockIdx.x * 64;
    const int hv = blockIdx.y;          // b*H + h
    const int b = hv / H_, h = hv % H_;
    const int src0 = h * 192 + 128;
#pragma unroll
    for (int c = 0; c < 2; ++c) {
        int i = tid + c * 256;
        int row = i >> 3, seg = i & 7;  // row = t-within-tile
        bf16x8 v = *(const bf16x8*)(qkv + (size_t)(b * T_ + t0 + row) * C3_ +
                                    src0 + seg * 8);
        *(bf16x8*)(tl + row * 64 + ((seg ^ (row & 7)) * 8)) = v;
    }
    __syncthreads();
#pragma unroll
    for (int c = 0; c < 2; ++c) {
        int i = tid + c * 256;
        int d = i >> 3, ts = i & 7;
        bf16x8 o;
#pragma unroll
        for (int j = 0; j < 8; ++j)
            o[j] = tl[(ts * 8 + j) * 64 + (d ^ (j * 8))];
        *(bf16x8*)(vt + (size_t)(hv * 64 + d) * T_ + t0 + ts * 8) = o;
    }
}

// ---------------------------------------------------------------------------
// Causal flash attention, swapped-QK^T. Depth-2 prefetch (3 buffers),
// raw s_barrier + counted vmcnt. Grid 768 flat, XCD-grouped per (b,h).
// ---------------------------------------------------------------------------
__global__ __launch_bounds__(256) void attn_kernel(const bf16* __restrict__ qkv,
                                                   const bf16* __restrict__ vt,
                                                   bf16* __restrict__ y) {
    const int flat = blockIdx.x;
    const int g = (flat & 7) * 6 + (flat >> 3) / 16;  // 0..47 = b*H+h
    const int qt = (flat >> 3) & 15;
    const int h = g % H_, b = g / H_, hv = g;

    const int tid = threadIdx.x, l = tid & 63, w = tid >> 6;
    const int lr = l & 15, lh = l >> 4, d0 = lh * 8;
    const int bc = h * 192;

    __shared__ bf16 Kl[3][64 * 64];
    __shared__ bf16 Vl[3][64 * 64];
    __shared__ bf16 Pl[4][16 * 64];

    const int qg = qt * 64 + w * 16 + lr;
    const bf16* qp = qkv + (size_t)(b * T_ + qg) * C3_ + bc;
    bf16x8 qf0 = *(const bf16x8*)(qp + d0);
    bf16x8 qf1 = *(const bf16x8*)(qp + 32 + d0);

    const int srow = tid >> 3;
    const int ss = (tid & 7) ^ (srow & 7);
    const bf16* k0p = qkv + (size_t)(b * T_ + srow) * C3_ + bc + 64 + ss * 8;
    const bf16* k1p = k0p + (size_t)32 * C3_;
    const bf16* v0p = vt + (size_t)(hv * 64 + srow) * T_ + ss * 8;
    const bf16* v1p = v0p + (size_t)32 * T_;

#define ATTN_STAGE(buf, kc)                                                    \
    {                                                                          \
        GLOAD_LDS16(k0p + (size_t)(kc) * 64 * C3_, &Kl[buf][tid * 8]);         \
        GLOAD_LDS16(v0p + (kc) * 64, &Vl[buf][tid * 8]);                       \
        GLOAD_LDS16(k1p + (size_t)(kc) * 64 * C3_, &Kl[buf][(tid + 256) * 8]); \
        GLOAD_LDS16(v1p + (kc) * 64, &Vl[buf][(tid + 256) * 8]);               \
    }

    f32x4 acc_o[4] = {};
    float m_run = -1e30f, l_run = 0.f;
    const float SCL = 0.125f * 1.44269504089f;  // 1/sqrt(HD) * log2(e)

    ATTN_STAGE(0, 0);
    if (qt >= 1) ATTN_STAGE(1, 1);

    int cur = 0, nxt = 2;
    for (int kc = 0; kc <= qt; ++kc) {
        if (kc + 2 <= qt) {
            ATTN_STAGE(nxt, kc + 2);
            asm volatile("s_waitcnt vmcnt(8)" ::: "memory");
        } else if (kc + 1 <= qt) {
            asm volatile("s_waitcnt vmcnt(4)" ::: "memory");
        } else {
            asm volatile("s_waitcnt vmcnt(0)" ::: "memory");
        }
        __builtin_amdgcn_s_barrier();  // K/V stage(kc) visible

        const bf16* Kb = Kl[cur];
        const bf16* Vb = Vl[cur];

        // S^T = K Q^T : lane holds S[k = kc*64+nt*16+lh*4+r][q = qg]
        f32x4 st[4];
#pragma unroll
        for (int nt = 0; nt < 4; ++nt) {
            int R = nt * 16 + lr;
            const bf16* kb = Kb + R * 64;
            bf16x8 k0 = *(const bf16x8*)(kb + (lh ^ (R & 7)) * 8);
            bf16x8 k1 = *(const bf16x8*)(kb + ((4 + lh) ^ (R & 7)) * 8);
            f32x4 a = {};
            a = mfma16(k0, qf0, a);
            st[nt] = mfma16(k1, qf1, a);
        }

        // softmax in log2 domain; lane owns q-row qg, 16 k-values
        const int diag = (kc == qt);
        float p[16], pmax = -1e30f;
#pragma unroll
        for (int nt = 0; nt < 4; ++nt)
#pragma unroll
            for (int r = 0; r < 4; ++r) {
                float v = st[nt][r] * SCL;
                if (diag) {
                    int kg = kc * 64 + nt * 16 + lh * 4 + r;
                    if (kg > qg) v = -1e38f;
                }
                p[nt * 4 + r] = v;
                pmax = fmaxf(pmax, v);
            }
        pmax = fmaxf(pmax, __shfl_xor(pmax, 16, 64));
        pmax = fmaxf(pmax, __shfl_xor(pmax, 32, 64));

        if (!__all(pmax - m_run <= 8.0f)) {  // defer-max (T13), THR=8 (log2)
            float mnew = fmaxf(m_run, pmax);
            float sc = exp2f(m_run - mnew);
            l_run *= sc;
            m_run = mnew;
#pragma unroll
            for (int r = 0; r < 4; ++r) {
                float sq = __shfl(sc, lh * 4 + r, 64);
#pragma unroll
                for (int nt = 0; nt < 4; ++nt) acc_o[nt][r] *= sq;
            }
        }

        float lsum = 0.f;
#pragma unroll
        for (int i = 0; i < 16; ++i) {
            p[i] = exp2f(p[i] - m_run);
            lsum += p[i];
        }
        lsum += __shfl_xor(lsum, 16, 64);
        lsum += __shfl_xor(lsum, 32, 64);
        l_run += lsum;

        // P -> Pl[q_local = lr][k], swizzled rows
        {
            char* pw = (char*)&Pl[w][0];
            int swz = (lr & 7) << 4;
#pragma unroll
            for (int nt = 0; nt < 4; ++nt)
#pragma unroll
                for (int rr = 0; rr < 2; ++rr) {
                    int kk = nt * 16 + lh * 4 + rr * 2;
                    bf16x2 pr = {(bf16)p[nt * 4 + rr * 2],
                                 (bf16)p[nt * 4 + rr * 2 + 1]};
                    *(bf16x2*)(pw + lr * 128 + ((kk * 2) ^ swz)) = pr;
                }
        }

        // PV: a-frag = Pl rows (q_local), b-frag = Vl rows (d)
        {
            const bf16* pb = &Pl[w][0] + lr * 64;
            bf16x8 pa0 = *(const bf16x8*)(pb + (lh ^ (lr & 7)) * 8);
            bf16x8 pa1 = *(const bf16x8*)(pb + ((4 + lh) ^ (lr & 7)) * 8);
#pragma unroll
            for (int nt = 0; nt < 4; ++nt) {
                int R = nt * 16 + lr;
                const bf16* vb = Vb + R * 64;
                bf16x8 v0 = *(const bf16x8*)(vb + (lh ^ (R & 7)) * 8);
                bf16x8 v1 = *(const bf16x8*)(vb + ((4 + lh) ^ (R & 7)) * 8);
                acc_o[nt] = mfma16(pa0, v0, acc_o[nt]);
                acc_o[nt] = mfma16(pa1, v1, acc_o[nt]);
            }
        }
        asm volatile("s_waitcnt lgkmcnt(0)" ::: "memory");
        __builtin_amdgcn_s_barrier();  // all reads of buf[cur] done

        cur = (cur == 2) ? 0 : cur + 1;
        nxt = (nxt == 2) ? 0 : nxt + 1;
    }

    float rl = 1.0f / l_run;
#pragma unroll
    for (int r = 0; r < 4; ++r) {
        float rq = __shfl(rl, lh * 4 + r, 64);
        int q = qt * 64 + w * 16 + lh * 4 + r;
#pragma unroll
        for (int nt = 0; nt < 4; ++nt)
            y[(size_t)(b * T_ + q) * C_ + h * 64 + nt * 16 + lr] =
                (bf16)(acc_o[nt][r] * rq);
    }
#undef ATTN_STAGE
}

// ---------------------------------------------------------------------------
extern "C" void kernel_launch(void* const* d_in, const int* in_sizes, int n_in,
                              void* d_out, int out_size, void* d_ws, size_t ws_size,
                              hipStream_t stream) {
    (void)in_sizes; (void)n_in; (void)out_size; (void)ws_size;
    const float* x     = (const float*)d_in[0];
    const float* ln1_s = (const float*)d_in[1];
    const float* ln1_b = (const float*)d_in[2];
    const float* Wqkv  = (const float*)d_in[3];
    const float* bqkv  = (const float*)d_in[4];
    const float* Wo    = (const float*)d_in[5];
    const float* bo    = (const float*)d_in[6];
    const float* ln2_s = (const float*)d_in[7];
    const float* ln2_b = (const float*)d_in[8];
    const float* Wfc   = (const float*)d_in[9];
    const float* bfc   = (const float*)d_in[10];
    const float* Wproj = (const float*)d_in[11];
    const float* bproj = (const float*)d_in[12];

    char* ws = (char*)d_ws;
    float* x2     = (float*)(ws);
    bf16*  vtbuf  = (bf16*)(ws);                      // aliases x2 (live: vtrans..attn)
    bf16*  fcbuf  = (bf16*)(ws + 12582912);
    bf16*  WprojT = (bf16*)(ws + 37748736);
    bf16*  lnbuf  = (bf16*)(ws + 42467328);
    float* parts  = (float*)(ws + 42467328);          // aliases lnbuf+qkv (live: proj..reduce)
    bf16*  qkv    = (bf16*)(ws + 48758784);
    bf16*  WqkvT  = (bf16*)(ws + 67633152);
    bf16*  WoT    = (bf16*)(ws + 71172096);
    bf16*  WfcT   = (bf16*)(ws + 72351744);

    tcast_all_kernel<<<dim3(6912), dim3(32, 8), 0, stream>>>(
        Wqkv, Wo, Wfc, Wproj, WqkvT, WoT, WfcT, WprojT);

    ln_kernel<<<M_, 256, 0, stream>>>(x, ln1_s, ln1_b, lnbuf);

    gemm_kernel<EPI_BF16, 4><<<dim3(576, 1), 256, 0, stream>>>(
        lnbuf, WqkvT, bqkv, nullptr, qkv, C3_, C_, 18);

    vtrans_kernel<<<dim3(T_ / 64, B_ * H_), 256, 0, stream>>>(qkv, vtbuf);

    attn_kernel<<<dim3(768), 256, 0, stream>>>(qkv, vtbuf, lnbuf);

    // wo: N=768, K=768 -> MT=2, grid 384 (4 blocks/CU)
    gemm_kernel<EPI_RES_F32, 2><<<dim3(384, 1), 256, 0, stream>>>(
        lnbuf, WoT, bo, x, x2, C_, C_, 6);

    ln_kernel<<<M_, 256, 0, stream>>>(x2, ln2_s, ln2_b, lnbuf);

    // fc: 32 M-tiles x 24 N-tiles = 768 blocks
    gemm_kernel<EPI_GELU_BF16, 4><<<dim3(768, 1), 256, 0, stream>>>(
        lnbuf, WfcT, bfc, nullptr, fcbuf, C4_, C_, 24);

    // proj: MT=4 + split-K=2 (round-9: MT=2 no-split measured 52us; revert)
    gemm_kernel<EPI_PARTIAL, 4><<<dim3(192, 2), 256, 0, stream>>>(
        fcbuf, WprojT, nullptr, nullptr, parts, C_, C4_, 6);

    reduce2_kernel<<<dim3((M_ * C_) / 1024), 256, 0, stream>>>(parts, bproj, x2,
                                                               (float*)d_out);
}